// Round 2
// baseline (15727.985 us; speedup 1.0000x reference)
//
#include <hip/hip_runtime.h>
#include <hip/hip_bf16.h>

// LSTM (B=256, T=512, I=64, H=512, O=64) on MI355X.
// Batch-partitioned persistent kernel: 16 WGs x 16 batch rows, f16 MFMA
// (16x16x32) with fp32 accum, W_hh/W_ih pre-packed to exact B-frag order.
// No inter-WG sync. Round-1 changes (theory-only, no bench yet):
//   - double-buffered h & x in LDS  -> ONE __syncthreads per timestep
//     (halves vmcnt(0) barrier drains of the weight-load pipeline)
//   - x(t+1) global load issued right after barrier, LDS store after MFMAs
//   - bias folded into MFMA C-init (exact; saves 64 v_add/lane/step)
//   - pack kernel vectorized (float4 loads, f16x8 store) - it's on the
//     graph-replayed timed path
// Fallback plan if per-CU L2 path throttles (step >> 5us): 2D batch x gate
// partition w/ grid sync, or fp8 weight storage.

#define T_STEPS 512
#define ISZ 64
#define HSZ 512
#define BATCH 256
#define OSZ 64

#define HPITCH 520   // h LDS pitch (halves); 1040 B -> bank stride 4, no pathological conflicts
#define XPITCH 72

typedef _Float16 f16x8 __attribute__((ext_vector_type(8)));
typedef float f32x4 __attribute__((ext_vector_type(4)));

// ---------------- pack kernel: fp32 weights -> fp16 fragment-ordered ----------------
// whh_pk[tile][ks][lane][j] = W_hh[tile*16 + (lane&15)][ks*32 + (lane>>4)*8 + j]
// wih_pk[tile][ks][lane][j] = W_ih[tile*16 + (lane&15)][ks*32 + (lane>>4)*8 + j]
// bias[g] = b_ih[g] + b_hh[g];  wfcT[j][o] = W_fc[o][j]
#define N_WHH (128*16*64)
#define N_WIH (128*2*64)
#define N_BIAS 2048
#define N_WFC (512*64)
#define N_PACK (N_WHH + N_WIH + N_BIAS + N_WFC)

__global__ void pack_kernel(const float* __restrict__ W_ih, const float* __restrict__ W_hh,
                            const float* __restrict__ b_ih, const float* __restrict__ b_hh,
                            const float* __restrict__ W_fc,
                            _Float16* __restrict__ whh_pk, _Float16* __restrict__ wih_pk,
                            float* __restrict__ bias, float* __restrict__ wfcT) {
    int tid = blockIdx.x * 256 + threadIdx.x;
    if (tid < N_WHH) {
        int lane = tid & 63, ks = (tid >> 6) & 15, tile = tid >> 10;
        int g = tile * 16 + (lane & 15);
        int k = ks * 32 + (lane >> 4) * 8;
        const float4* src = (const float4*)(W_hh + (size_t)g * HSZ + k);
        float4 v0 = src[0], v1 = src[1];
        f16x8 o;
        o[0] = (_Float16)v0.x; o[1] = (_Float16)v0.y; o[2] = (_Float16)v0.z; o[3] = (_Float16)v0.w;
        o[4] = (_Float16)v1.x; o[5] = (_Float16)v1.y; o[6] = (_Float16)v1.z; o[7] = (_Float16)v1.w;
        *(f16x8*)(whh_pk + (size_t)tid * 8) = o;
        return;
    }
    tid -= N_WHH;
    if (tid < N_WIH) {
        int lane = tid & 63, ks = (tid >> 6) & 1, tile = tid >> 7;
        int g = tile * 16 + (lane & 15);
        int k = ks * 32 + (lane >> 4) * 8;
        const float4* src = (const float4*)(W_ih + (size_t)g * ISZ + k);
        float4 v0 = src[0], v1 = src[1];
        f16x8 o;
        o[0] = (_Float16)v0.x; o[1] = (_Float16)v0.y; o[2] = (_Float16)v0.z; o[3] = (_Float16)v0.w;
        o[4] = (_Float16)v1.x; o[5] = (_Float16)v1.y; o[6] = (_Float16)v1.z; o[7] = (_Float16)v1.w;
        *(f16x8*)(wih_pk + (size_t)tid * 8) = o;
        return;
    }
    tid -= N_WIH;
    if (tid < N_BIAS) { bias[tid] = b_ih[tid] + b_hh[tid]; return; }
    tid -= N_BIAS;
    if (tid < N_WFC) {
        int j = tid >> 6, o = tid & 63;
        wfcT[j * 64 + o] = W_fc[o * HSZ + j];
    }
}

// ---------------- math helpers ----------------
__device__ __forceinline__ float sigmoid_f(float x) {
    return __builtin_amdgcn_rcpf(1.f + __expf(-x));
}
__device__ __forceinline__ float tanh_f(float x) {
    // tanh(x) = 1 - 2/(e^{2x}+1); exact at +-inf
    return 1.f - 2.f * __builtin_amdgcn_rcpf(1.f + __expf(2.f * x));
}

// ---------------- main persistent kernel ----------------
// grid = 16 blocks x 512 threads (8 waves). Block b owns batch rows [16b,16b+16).
// Wave w owns hidden units [64w,64w+64): gate tiles tile = gb*32 + w*4 + a
// (gb=0..3 -> i,f,g,o at gate offset gb*512). One barrier per timestep.
__global__ __launch_bounds__(512, 2)
void lstm_kernel(const float* __restrict__ x,
                 const _Float16* __restrict__ whh_pk, const _Float16* __restrict__ wih_pk,
                 const float* __restrict__ bias, const float* __restrict__ wfcT,
                 const float* __restrict__ b_fc, float* __restrict__ out) {
    __shared__ _Float16 hb[2][16 * HPITCH];   // 33.3 KB
    __shared__ _Float16 xb[2][16 * XPITCH];   //  4.6 KB

    const int tid = threadIdx.x;
    const int lane = tid & 63;
    const int w = tid >> 6;          // wave 0..7
    const int row = lane & 15;       // A-frag batch row / B-frag gate-in-tile
    const int kg = lane >> 4;        // k-group 0..3
    const int brow0 = blockIdx.x * 16;

    // zero h(0) buffer
    for (int i = tid; i < 16 * HPITCH; i += 512) hb[0][i] = (_Float16)0.f;

    // x staging mapping: 16 rows x 64 cols, 2 floats per thread
    const int xs_row = tid >> 5;
    const int xs_col = (tid & 31) * 2;
    const float* xs_base = x + ((size_t)(brow0 + xs_row) * T_STEPS) * ISZ + xs_col;

    // stage x(0)
    {
        float2 v = *(const float2*)(xs_base);
        xb[0][xs_row * XPITCH + xs_col]     = (_Float16)v.x;
        xb[0][xs_row * XPITCH + xs_col + 1] = (_Float16)v.y;
    }

    // per-lane biases (same for all 4 rows of a C tile)
    float bia[4][4];
    #pragma unroll
    for (int gb = 0; gb < 4; ++gb)
        #pragma unroll
        for (int a = 0; a < 4; ++a)
            bia[gb][a] = bias[gb * 512 + w * 64 + a * 16 + row];

    // c state: cst[a][r] <-> (m = 4*kg + r, hid = w*64 + a*16 + row)
    f32x4 cst[4];
    #pragma unroll
    for (int a = 0; a < 4; ++a) cst[a] = (f32x4){0.f, 0.f, 0.f, 0.f};

    for (int t = 0; t < T_STEPS; ++t) {
        const int cur = t & 1, nxt = cur ^ 1;
        __syncthreads();   // h(t) in hb[cur], x(t) in xb[cur] now visible

        // issue x(t+1) load immediately; LDS store deferred past MFMA phase
        float2 xv;
        const bool havex = (t + 1) < T_STEPS;
        if (havex) xv = *(const float2*)(xs_base + (size_t)(t + 1) * ISZ);

        // init acc with bias (C-operand of first MFMA)
        f32x4 acc[4][4];
        #pragma unroll
        for (int gb = 0; gb < 4; ++gb)
            #pragma unroll
            for (int a = 0; a < 4; ++a) {
                float b0 = bia[gb][a];
                acc[gb][a] = (f32x4){b0, b0, b0, b0};
            }

        // ---- x_t @ W_ih^T (K=64) ----
        #pragma unroll
        for (int ks = 0; ks < 2; ++ks) {
            f16x8 af = *(const f16x8*)(&xb[cur][row * XPITCH + kg * 8 + ks * 32]);
            #pragma unroll
            for (int gb = 0; gb < 4; ++gb)
                #pragma unroll
                for (int a = 0; a < 4; ++a) {
                    int tile = gb * 32 + w * 4 + a;
                    f16x8 bf = *(const f16x8*)(&wih_pk[((size_t)(tile * 2 + ks) * 64 + lane) * 8]);
                    acc[gb][a] = __builtin_amdgcn_mfma_f32_16x16x32_f16(af, bf, acc[gb][a], 0, 0, 0);
                }
        }
        // ---- h_t @ W_hh^T (K=512) ----
        #pragma unroll 4
        for (int ks = 0; ks < 16; ++ks) {
            f16x8 af = *(const f16x8*)(&hb[cur][row * HPITCH + kg * 8 + ks * 32]);
            #pragma unroll
            for (int gb = 0; gb < 4; ++gb)
                #pragma unroll
                for (int a = 0; a < 4; ++a) {
                    int tile = gb * 32 + w * 4 + a;
                    f16x8 bf = *(const f16x8*)(&whh_pk[((size_t)(tile * 16 + ks) * 64 + lane) * 8]);
                    acc[gb][a] = __builtin_amdgcn_mfma_f32_16x16x32_f16(af, bf, acc[gb][a], 0, 0, 0);
                }
        }

        // land x(t+1) into the other buffer (load issued ~1 MFMA-phase ago)
        if (havex) {
            xb[nxt][xs_row * XPITCH + xs_col]     = (_Float16)xv.x;
            xb[nxt][xs_row * XPITCH + xs_col + 1] = (_Float16)xv.y;
        }

        // ---- cell update; i/f/g/o share (lane,reg) position across gb ----
        #pragma unroll
        for (int a = 0; a < 4; ++a) {
            #pragma unroll
            for (int r = 0; r < 4; ++r) {
                float iv = sigmoid_f(acc[0][a][r]);
                float fv = sigmoid_f(acc[1][a][r]);
                float gv = tanh_f   (acc[2][a][r]);
                float ov = sigmoid_f(acc[3][a][r]);
                float c = fv * cst[a][r] + iv * gv;
                cst[a][r] = c;
                float hv = ov * tanh_f(c);
                hb[nxt][(4 * kg + r) * HPITCH + w * 64 + a * 16 + row] = (_Float16)hv;
            }
        }
    }
    __syncthreads();   // h(T) complete in hb[T_STEPS & 1] == hb[0]

    // ---- final FC: out[m][o] = relu(h_T[m]) @ W_fc^T + b_fc ----
    #pragma unroll
    for (int rr = 0; rr < 2; ++rr) {
        int m = w * 2 + rr;
        float acco = b_fc[lane];
        #pragma unroll 8
        for (int j = 0; j < HSZ; ++j) {
            float hv = (float)hb[0][m * HPITCH + j];   // LDS broadcast
            hv = fmaxf(hv, 0.f);
            acco += hv * wfcT[j * 64 + lane];
        }
        out[(size_t)(brow0 + m) * OSZ + lane] = acco;
    }
}

// ---------------- launch ----------------
extern "C" void kernel_launch(void* const* d_in, const int* in_sizes, int n_in,
                              void* d_out, int out_size, void* d_ws, size_t ws_size,
                              hipStream_t stream) {
    (void)in_sizes; (void)n_in; (void)out_size; (void)ws_size;
    const float* x    = (const float*)d_in[0];
    const float* W_ih = (const float*)d_in[1];
    const float* W_hh = (const float*)d_in[2];
    const float* b_ih = (const float*)d_in[3];
    const float* b_hh = (const float*)d_in[4];
    const float* W_fc = (const float*)d_in[5];
    const float* b_fc = (const float*)d_in[6];
    float* out = (float*)d_out;

    char* wsb = (char*)d_ws;
    _Float16* whh_pk = (_Float16*)wsb;                                  // 2 MB
    _Float16* wih_pk = (_Float16*)(wsb + 2097152);                      // 256 KB
    float*    bias   = (float*)   (wsb + 2097152 + 262144);             // 8 KB
    float*    wfcT   = (float*)   (wsb + 2097152 + 262144 + 8192);      // 128 KB

    dim3 pgrid((N_PACK + 255) / 256), pblk(256);
    hipLaunchKernelGGL(pack_kernel, pgrid, pblk, 0, stream,
                       W_ih, W_hh, b_ih, b_hh, W_fc, whh_pk, wih_pk, bias, wfcT);

    dim3 grid(16), blk(512);
    hipLaunchKernelGGL(lstm_kernel, grid, blk, 0, stream,
                       x, whh_pk, wih_pk, bias, wfcT, b_fc, out);
}